// Round 9
// baseline (151.610 us; speedup 1.0000x reference)
//
#include <hip/hip_runtime.h>

// GATConv single layer. N=50000, E=800000 (+N self loops), IN=128, H*C=128.
//
// R17 = R16 + SRC-OCTILE-SORTED BINS for agg L2 temporal locality.
//   Remaining budget (~103us ours) is dominated by gat_agg's 218MB random
//   hb-row gather (850K edges x 256B, src uniform-random -> L3-tier
//   accesses, ~6TB/s fabric => ~36us). hb is only 12.8MB; if all waves
//   process their edges in src-octile order (src/6250 -> 0..7), the
//   machine-wide instantaneous working set is ~1-2 octile slices
//   (1.6-3.2MB) -> resident per-XCD L2 (read-only copy per XCD, 34TB/s
//   aggregate). Implemented entirely in passB: two-pass drain —
//   (1) count per (node,octile) in LDS, (2) per-node prefix (yields deg),
//   (3) re-drain placing edges sorted. agg is byte-identical to R16
//   (isolates the locality variable). No capacity changes => no overflow
//   risk; stream-out still coalesced.
// R13/R15 lesson: 800K device atomics = ~50us wall; keep atomics CU-side.
// R16 lesson: LDS-staged coalesced A-tiles for gemm (kept).
// R9: no edge-weight precompute. R10: agg not latency-bound (hence
//   bandwidth-locality attack). R12: BIN=64 fixed-stride bins.
// Pipeline: gemm_passA | passB | gat_agg   (no memset, all on `stream`)
// No segment-max: logits are O(7), exp() safe in fp32; exp(e)/sum == softmax.

constexpr int N_NODES = 50000;
constexpr int N_EDGES = 800000;
constexpr int HC      = 128;
constexpr float NEG_SLOPE = 0.2f;
constexpr int M_TILES = N_NODES / 16;               // 3125
constexpr int NB_PASSA = 256;                       // blocks [0,256): pass A
constexpr int NB_GEMM  = 512;                       // blocks [256,768): gemm
constexpr int EPB      = N_EDGES / NB_PASSA;        // 3125 edges/block, exact
constexpr int BIN      = 64;  // slots/node: 1 self + <=63 in-edges
constexpr int NBKT     = 64;                        // dst buckets
constexpr int BW       = 782;                       // bucket width: 64*782=50048
constexpr int CAP      = 96;                        // seg capacity/block/bucket
constexpr int LDA      = 136;                       // LDS A row stride (bf16)
constexpr int NOCT     = 8;                         // src octiles (50000/6250)

typedef short short8 __attribute__((ext_vector_type(8)));
typedef float f32x4  __attribute__((ext_vector_type(4)));

__device__ inline unsigned short f2bf(float f) {   // RTNE
    unsigned int u = __float_as_uint(f);
    u += 0x7FFF + ((u >> 16) & 1);
    return (unsigned short)(u >> 16);
}

// ---- K1: pass A (edge bucketing, atomic-free global) || MFMA GEMM ----

__global__ __launch_bounds__(256) void gemm_passA(
    const float* __restrict__ x,             // [N,128] fp32
    const float* __restrict__ W,             // [k:128][n:128] fp32
    const float* __restrict__ att_src, const float* __restrict__ att_dst,
    const int* __restrict__ esrc, const int* __restrict__ edst,
    unsigned short* __restrict__ hb,         // [N,128] bf16
    float* __restrict__ a_src, float* __restrict__ a_dst,
    unsigned int* __restrict__ seg,          // [256][64][CAP] u32 packed
    int* __restrict__ seg_cnt)               // [256][64]
{
    __shared__ int cnt_l[NBKT];
    __shared__ unsigned short As[2][16][LDA];    // 2 staged A-tiles, bf16
    if (blockIdx.x < NB_PASSA) {
        // ---- pass A: bucket edges into block-private segments ----
        const int p = blockIdx.x;
        if (threadIdx.x < NBKT) cnt_l[threadIdx.x] = 0;
        __syncthreads();
        const int e0 = p * EPB, e1 = e0 + EPB;
        for (int e = e0 + threadIdx.x; e < e1; e += 256) {
            const int d = edst[e];                   // coalesced
            const int s = esrc[e];
            const int b = d / BW;                    // 0..63 (magic-mul)
            const int pos = atomicAdd(&cnt_l[b], 1); // LDS atomic (CU-side)
            if (pos < CAP)                           // never fires (max ~80)
                seg[((p * NBKT) + b) * CAP + pos] =
                    ((unsigned int)s << 10) | (unsigned int)(d - b * BW);
        }
        __syncthreads();
        if (threadIdx.x < NBKT)
            seg_cnt[p * NBKT + threadIdx.x] = min(cnt_l[threadIdx.x], CAP);
        return;
    }
    // ---------------- GEMM part ----------------
    const int tid  = threadIdx.x;
    const int wave = tid >> 6;
    const int lane = tid & 63;
    const int n0   = (wave & 1) * 64;        // n-strip per wave
    const int l15  = lane & 15;
    const int quad = lane >> 4;

    // B frags direct from fp32 W (64 KB, L2-hot; amortized over ~3 tiles):
    // B[k=ks*32+quad*8+j][n=n0+16t+l15] = W[k*128+n]
    short8 bfrag[4][4];
    #pragma unroll
    for (int t = 0; t < 4; ++t)
        #pragma unroll
        for (int ks = 0; ks < 4; ++ks) {
            short8 b;
            #pragma unroll
            for (int j = 0; j < 8; ++j)
                b[j] = (short)f2bf(W[(ks * 32 + quad * 8 + j) * 128 + n0 + t * 16 + l15]);
            bfrag[t][ks] = b;
        }

    float asw[4], adw[4];                    // att weights, col = n0+t*16+l15
    #pragma unroll
    for (int t = 0; t < 4; ++t) {
        asw[t] = att_src[n0 + t * 16 + l15];
        adw[t] = att_dst[n0 + t * 16 + l15];
    }

    const int gb = blockIdx.x - NB_PASSA;    // 0..511
    for (int mtb = gb * 2; mtb < M_TILES; mtb += NB_GEMM * 2) {
        // ---- cooperative coalesced staging of tiles mtb, mtb+1 ----
        // 1024 float4 pieces; piece g: tile g>>9, row (g&511)>>5, col4 g&31.
        #pragma unroll
        for (int j = 0; j < 4; ++j) {
            const int g   = tid + j * 256;
            const int tl  = g >> 9;
            const int w   = g & 511;
            const int row = w >> 5;
            const int c4  = w & 31;
            const int mts = mtb + tl;
            if (mts < M_TILES) {
                const float4 u = *(const float4*)&x[(size_t)(mts * 16 + row) * 128 + c4 * 4];
                ushort4 v;
                v.x = f2bf(u.x); v.y = f2bf(u.y); v.z = f2bf(u.z); v.w = f2bf(u.w);
                *(ushort4*)&As[tl][row][c4 * 4] = v;     // 8B LDS store
            }
        }
        __syncthreads();

        const int mt = mtb + (wave >> 1);
        if (mt < M_TILES) {
            const int m0 = mt * 16;
            const int tl = wave >> 1;

            short8 afrag[4];                 // A[m=m0+l15][k=ks*32+quad*8+j]
            #pragma unroll
            for (int ks = 0; ks < 4; ++ks)
                afrag[ks] = *(const short8*)&As[tl][l15][ks * 32 + quad * 8];

            f32x4 acc[4];
            #pragma unroll
            for (int t = 0; t < 4; ++t) acc[t] = (f32x4){0.f, 0.f, 0.f, 0.f};

            #pragma unroll
            for (int ks = 0; ks < 4; ++ks)
                #pragma unroll
                for (int t = 0; t < 4; ++t)
                    acc[t] = __builtin_amdgcn_mfma_f32_16x16x32_bf16(afrag[ks], bfrag[t][ks], acc[t], 0, 0, 0);

            // C/D: row = m0 + quad*4 + r, col = n0 + t*16 + l15
            #pragma unroll
            for (int t = 0; t < 4; ++t)
                #pragma unroll
                for (int r = 0; r < 4; ++r)
                    hb[(m0 + quad * 4 + r) * 128 + n0 + t * 16 + l15] = f2bf(acc[t][r]);

            // fused attention dots: per lane, head g = n0/32 + (t>>1)
            float hs[2][4] = {{0.f,0.f,0.f,0.f},{0.f,0.f,0.f,0.f}};
            float hd[2][4] = {{0.f,0.f,0.f,0.f},{0.f,0.f,0.f,0.f}};
            #pragma unroll
            for (int t = 0; t < 4; ++t)
                #pragma unroll
                for (int r = 0; r < 4; ++r) {
                    hs[t >> 1][r] += acc[t][r] * asw[t];
                    hd[t >> 1][r] += acc[t][r] * adw[t];
                }
            #pragma unroll
            for (int off = 1; off < 16; off <<= 1)
                #pragma unroll
                for (int g = 0; g < 2; ++g)
                    #pragma unroll
                    for (int r = 0; r < 4; ++r) {
                        hs[g][r] += __shfl_xor(hs[g][r], off);
                        hd[g][r] += __shfl_xor(hd[g][r], off);
                    }
            if (l15 == 0) {
                const int hb0 = n0 >> 5;     // first head of this strip
                #pragma unroll
                for (int g = 0; g < 2; ++g)
                    #pragma unroll
                    for (int r = 0; r < 4; ++r) {
                        a_src[(m0 + quad * 4 + r) * 4 + hb0 + g] = hs[g][r];
                        a_dst[(m0 + quad * 4 + r) * 4 + hb0 + g] = hd[g][r];
                    }
            }
        }
        __syncthreads();                     // As reused next iteration
    }
}

// ---- K2: pass B — per-bucket LDS binning, SRC-OCTILE-SORTED bins ----

__global__ __launch_bounds__(256) void passB(
    const unsigned int* __restrict__ seg, const int* __restrict__ seg_cnt,
    int* __restrict__ deg, unsigned short* __restrict__ csr_bin)
{
    __shared__ unsigned short bin_l[BW * BIN];   // 100,096 B
    __shared__ int deg_l[BW];                    //   3,128 B
    __shared__ int oct_l[BW * NOCT];             //  25,024 B (counts->offsets)
    const int b   = blockIdx.x;                  // bucket = node range
    const int tid = threadIdx.x;
    const int nb  = min(BW, N_NODES - b * BW);   // 782 (734 for b=63)

    for (int i = tid; i < BW * NOCT; i += 256) oct_l[i] = 0;
    __syncthreads();

    const int cnt = seg_cnt[tid * NBKT + b];
    const uint4* s4 = (const uint4*)&seg[((size_t)(tid * NBKT) + b) * CAP];

    // drain pass 1: count (node, src-octile)
    for (int i = 0; i < cnt; i += 4) {
        const uint4 u = s4[i >> 2];
        const int rem = cnt - i;
        atomicAdd(&oct_l[(u.x & 1023u) * NOCT + (u.x >> 10) / 6250u], 1);
        if (rem > 1) atomicAdd(&oct_l[(u.y & 1023u) * NOCT + (u.y >> 10) / 6250u], 1);
        if (rem > 2) atomicAdd(&oct_l[(u.z & 1023u) * NOCT + (u.z >> 10) / 6250u], 1);
        if (rem > 3) atomicAdd(&oct_l[(u.w & 1023u) * NOCT + (u.w >> 10) / 6250u], 1);
    }
    __syncthreads();

    // per-node exclusive prefix over octiles; total = deg
    for (int nd = tid; nd < BW; nd += 256) {
        int s = 0;
        #pragma unroll
        for (int k = 0; k < NOCT; ++k) {
            const int c = oct_l[nd * NOCT + k];
            oct_l[nd * NOCT + k] = s;
            s += c;
        }
        deg_l[nd] = s;
    }
    __syncthreads();

    // drain pass 2: place edges src-octile-sorted (seg L2-hot re-read)
    for (int i = 0; i < cnt; i += 4) {
        const uint4 u = s4[i >> 2];
        const int rem = cnt - i;
        {
            const int doff = (int)(u.x & 1023u); const int src = (int)(u.x >> 10);
            const int pos = atomicAdd(&oct_l[doff * NOCT + src / 6250u], 1);
            if (pos < BIN - 1) bin_l[doff * BIN + 1 + pos] = (unsigned short)src;
        }
        if (rem > 1) {
            const int doff = (int)(u.y & 1023u); const int src = (int)(u.y >> 10);
            const int pos = atomicAdd(&oct_l[doff * NOCT + src / 6250u], 1);
            if (pos < BIN - 1) bin_l[doff * BIN + 1 + pos] = (unsigned short)src;
        }
        if (rem > 2) {
            const int doff = (int)(u.z & 1023u); const int src = (int)(u.z >> 10);
            const int pos = atomicAdd(&oct_l[doff * NOCT + src / 6250u], 1);
            if (pos < BIN - 1) bin_l[doff * BIN + 1 + pos] = (unsigned short)src;
        }
        if (rem > 3) {
            const int doff = (int)(u.w & 1023u); const int src = (int)(u.w >> 10);
            const int pos = atomicAdd(&oct_l[doff * NOCT + src / 6250u], 1);
            if (pos < BIN - 1) bin_l[doff * BIN + 1 + pos] = (unsigned short)src;
        }
    }
    __syncthreads();

    // coalesced stream-out: csr_bin rows + deg for this node range
    uint4* dst = (uint4*)(csr_bin + (size_t)b * BW * BIN);
    const uint4* srcl = (const uint4*)bin_l;
    const int nvec = nb * BIN / 8;               // 16B vectors (BIN*2B/16)
    for (int k = tid; k < nvec; k += 256) dst[k] = srcl[k];
    for (int i = tid; i < nb; i += 256) deg[b * BW + i] = deg_l[i];
}

// ---- K3: aggregation — wave/node, single <=64-edge batch, 4 in flight ----
// (byte-identical to R16: isolates the bin-ordering variable)

__global__ __launch_bounds__(256) void gat_agg(
    const int* __restrict__ deg, const unsigned short* __restrict__ csr_bin,
    const unsigned short* __restrict__ hb, const float* __restrict__ a_src,
    const float* __restrict__ a_dst, const float* __restrict__ bias,
    float* __restrict__ out)
{
    __shared__ float ws[4][256];             // [wave][edge*4 + head]
    const int wv = threadIdx.x >> 6;
    const int node = blockIdx.x * 4 + wv;
    if (node >= N_NODES) return;
    const int lane = threadIdx.x & 63;
    const int q    = lane >> 4;              // quarter: which edge of the 4
    const int li   = lane & 15;
    const int ch0  = li * 8;                 // 8 channels per lane
    const int hd   = li >> 2;                // head of my channels (ch0/32)
    const float4 ad4 = *(const float4*)&a_dst[node * 4];
    int m = deg[node] + 1;                   // self loop included
    if (m > BIN) m = BIN;                    // never fires (max deg ~45)

    // lane 0 = self loop (synthesized), lanes [1,m) = binned in-edges
    int sv = 0;
    if (lane < m)
        sv = (lane == 0) ? node : (int)csr_bin[(size_t)node * BIN + lane];
    if (lane < m) {
        const float4 av = *(const float4*)&a_src[sv * 4];
        float t; float4 w4;
        t = av.x + ad4.x; t = t > 0.f ? t : NEG_SLOPE * t; w4.x = __expf(t);
        t = av.y + ad4.y; t = t > 0.f ? t : NEG_SLOPE * t; w4.y = __expf(t);
        t = av.z + ad4.z; t = t > 0.f ? t : NEG_SLOPE * t; w4.z = __expf(t);
        t = av.w + ad4.w; t = t > 0.f ? t : NEG_SLOPE * t; w4.w = __expf(t);
        *(float4*)&ws[wv][lane * 4] = w4;    // all 4 head weights for my edge
    }

    float acc[8] = {0.f,0.f,0.f,0.f,0.f,0.f,0.f,0.f};
    float dsum = 0.f;

    // software-pipelined: prefetch next 4-edge group's h rows while
    // accumulating the current group (8 rows in flight per wave).
    const int i0 = (q < m) ? q : 0;
    uint4 hv = *(const uint4*)&hb[(size_t)__shfl(sv, i0) * 128 + ch0];
    for (int j = 0; j < m; j += 4) {
        const int ei  = j + q;
        const int idx = ei < m ? ei : j;     // edge whose row is in hv
        const int ein = ei + 4;
        const int idxn = ein < m ? ein : 0;  // next group's edge (clamped)
        const int s_nxt = __shfl(sv, idxn);
        const uint4 hvn = *(const uint4*)&hb[(size_t)s_nxt * 128 + ch0];
        float w = ws[wv][idx * 4 + hd];
        if (ei >= m) w = 0.f;
        acc[0] += w * __uint_as_float(hv.x << 16);
        acc[1] += w * __uint_as_float(hv.x & 0xFFFF0000u);
        acc[2] += w * __uint_as_float(hv.y << 16);
        acc[3] += w * __uint_as_float(hv.y & 0xFFFF0000u);
        acc[4] += w * __uint_as_float(hv.z << 16);
        acc[5] += w * __uint_as_float(hv.z & 0xFFFF0000u);
        acc[6] += w * __uint_as_float(hv.w << 16);
        acc[7] += w * __uint_as_float(hv.w & 0xFFFF0000u);
        dsum += w;
        hv = hvn;
    }

    // combine the four quarters (disjoint edge subsets, same channels)
    #pragma unroll
    for (int off = 16; off <= 32; off <<= 1) {
        #pragma unroll
        for (int r = 0; r < 8; ++r) acc[r] += __shfl_xor(acc[r], off);
        dsum += __shfl_xor(dsum, off);
    }
    if (q == 0) {
        const float inv = 1.f / dsum;        // dsum >= exp(self) > 0
        const float4 b0 = *(const float4*)&bias[ch0];
        const float4 b1 = *(const float4*)&bias[ch0 + 4];
        float4 o0, o1;
        o0.x = acc[0]*inv + b0.x; o0.y = acc[1]*inv + b0.y;
        o0.z = acc[2]*inv + b0.z; o0.w = acc[3]*inv + b0.w;
        o1.x = acc[4]*inv + b1.x; o1.y = acc[5]*inv + b1.y;
        o1.z = acc[6]*inv + b1.z; o1.w = acc[7]*inv + b1.w;
        *(float4*)&out[(size_t)node * HC + ch0]     = o0;
        *(float4*)&out[(size_t)node * HC + ch0 + 4] = o1;
    }
}

extern "C" void kernel_launch(void* const* d_in, const int* in_sizes, int n_in,
                              void* d_out, int out_size, void* d_ws, size_t ws_size,
                              hipStream_t stream) {
    const float* x       = (const float*)d_in[0];
    const int*   ei      = (const int*)  d_in[1];   // [2,E]: row0=src, row1=dst
    const float* W       = (const float*)d_in[2];
    const float* att_src = (const float*)d_in[3];
    const float* att_dst = (const float*)d_in[4];
    const float* bias    = (const float*)d_in[5];
    float* out = (float*)d_out;

    // ws layout (~28 MB): hb | a_src | a_dst | csr_bin(u16) | deg | seg | seg_cnt
    char* p = (char*)d_ws;
    unsigned short* hb  = (unsigned short*)p; p += (size_t)N_NODES * HC * 2;  // 12.8 MB
    float* a_src = (float*)p; p += (size_t)N_NODES * 4 * 4;                   // 800 KB
    float* a_dst = (float*)p; p += (size_t)N_NODES * 4 * 4;
    unsigned short* csr_bin = (unsigned short*)p; p += (size_t)NBKT * BW * BIN * 2; // 6.41 MB
    int* deg     = (int*)p;   p += N_NODES * 4;
    unsigned int* seg = (unsigned int*)p; p += (size_t)NB_PASSA * NBKT * CAP * 4;  // 6.29 MB
    int* seg_cnt = (int*)p;   p += NB_PASSA * NBKT * 4;                            // 64 KB

    const int* esrc = ei;
    const int* edst = ei + N_EDGES;

    gemm_passA<<<NB_PASSA + NB_GEMM, 256, 0, stream>>>(x, W, att_src, att_dst,
                                                       esrc, edst, hb, a_src, a_dst,
                                                       seg, seg_cnt);
    passB     <<<NBKT, 256, 0, stream>>>(seg, seg_cnt, deg, csr_bin);
    gat_agg   <<<(N_NODES + 3) / 4, 256, 0, stream>>>(deg, csr_bin, hb, a_src,
                                                      a_dst, bias, out);
}

// Round 10
// 145.906 us; speedup vs baseline: 1.0391x; 1.0391x over previous
//
#include <hip/hip_runtime.h>

// GATConv single layer. N=50000, E=800000 (+N self loops), IN=128, H*C=128.
//
// R18 = R16 (octile sort REVERTED: R17 +4.6us, agg gain zero — per-node
// sort can't create machine-wide temporal alignment at deg~17) with:
//   1) 256-BUCKET passB (was 64): R16's passB used only 64 blocks (25% of
//      CUs) with 49-deep serial drains. Now: bucket = dst/196, CAP=36
//      (Binomial(3125,196/50000) mu=12.2, z=6.8; clamp+absmax guards),
//      256 blocks x ~12-edge drains, 26KB LDS, coalesced stream-out.
//      Predicted passB ~14 -> ~5us.
//   2) agg 2-GROUP-AHEAD prefetch: 8 rows in flight per wave (was 4).
//      If CU MSHR pool isn't saturated at ~29 waves/CU this cuts agg;
//      if agg is at the fabric random-gather floor (~5-6TB/s for its
//      218MB) it's neutral — discriminating either way.
// Budget model (R12/13/15/16 triangulation): OH~65 (harness fills/resets),
//   gemm_passA~20, passB~14, agg~40-43 (fabric floor candidate).
// R13/R15: 800K device atomics = ~50us wall; all atomics stay CU-side.
// R16: LDS-staged coalesced A-tiles for gemm. R9: no edge-weight
//   precompute. R12: fixed-stride bins, self-loop synthesized in agg.
// Pipeline: gemm_passA | passB | gat_agg   (no memset, all on `stream`)
// No segment-max: logits are O(7), exp() safe in fp32; exp(e)/sum == softmax.

constexpr int N_NODES = 50000;
constexpr int N_EDGES = 800000;
constexpr int HC      = 128;
constexpr float NEG_SLOPE = 0.2f;
constexpr int M_TILES = N_NODES / 16;               // 3125
constexpr int NB_PASSA = 256;                       // blocks [0,256): pass A
constexpr int NB_GEMM  = 512;                       // blocks [256,768): gemm
constexpr int EPB      = N_EDGES / NB_PASSA;        // 3125 edges/block, exact
constexpr int BIN      = 64;  // slots/node: 1 self + <=63 in-edges
constexpr int NBKT     = 256;                       // dst buckets
constexpr int BWK      = 196;                       // bucket width: 256*196=50176
constexpr int CAP      = 36;                        // seg cap/block/bucket (16B-mult)
constexpr int LDA      = 136;                       // LDS A row stride (bf16)

typedef short short8 __attribute__((ext_vector_type(8)));
typedef float f32x4  __attribute__((ext_vector_type(4)));

__device__ inline unsigned short f2bf(float f) {   // RTNE
    unsigned int u = __float_as_uint(f);
    u += 0x7FFF + ((u >> 16) & 1);
    return (unsigned short)(u >> 16);
}

// ---- K1: pass A (edge bucketing, atomic-free global) || MFMA GEMM ----

__global__ __launch_bounds__(256) void gemm_passA(
    const float* __restrict__ x,             // [N,128] fp32
    const float* __restrict__ W,             // [k:128][n:128] fp32
    const float* __restrict__ att_src, const float* __restrict__ att_dst,
    const int* __restrict__ esrc, const int* __restrict__ edst,
    unsigned short* __restrict__ hb,         // [N,128] bf16
    float* __restrict__ a_src, float* __restrict__ a_dst,
    unsigned int* __restrict__ seg,          // [256][NBKT][CAP] u32 packed
    int* __restrict__ seg_cnt)               // [256][NBKT]
{
    __shared__ int cnt_l[NBKT];
    __shared__ unsigned short As[2][16][LDA];    // 2 staged A-tiles, bf16
    if (blockIdx.x < NB_PASSA) {
        // ---- pass A: bucket edges into block-private segments ----
        const int p = blockIdx.x;
        cnt_l[threadIdx.x] = 0;                  // 256 threads, one each
        __syncthreads();
        const int e0 = p * EPB, e1 = e0 + EPB;
        for (int e = e0 + threadIdx.x; e < e1; e += 256) {
            const int d = edst[e];                   // coalesced
            const int s = esrc[e];
            const int b = d / BWK;                   // 0..255 (magic-mul)
            const int pos = atomicAdd(&cnt_l[b], 1); // LDS atomic (CU-side)
            if (pos < CAP)                           // never fires (mu 12, z 6.8)
                seg[((p * NBKT) + b) * CAP + pos] =
                    ((unsigned int)s << 8) | (unsigned int)(d - b * BWK);
        }
        __syncthreads();
        seg_cnt[p * NBKT + threadIdx.x] = min(cnt_l[threadIdx.x], CAP);
        return;
    }
    // ---------------- GEMM part ----------------
    const int tid  = threadIdx.x;
    const int wave = tid >> 6;
    const int lane = tid & 63;
    const int n0   = (wave & 1) * 64;        // n-strip per wave
    const int l15  = lane & 15;
    const int quad = lane >> 4;

    // B frags direct from fp32 W (64 KB, L2-hot; amortized over ~3 tiles):
    // B[k=ks*32+quad*8+j][n=n0+16t+l15] = W[k*128+n]
    short8 bfrag[4][4];
    #pragma unroll
    for (int t = 0; t < 4; ++t)
        #pragma unroll
        for (int ks = 0; ks < 4; ++ks) {
            short8 b;
            #pragma unroll
            for (int j = 0; j < 8; ++j)
                b[j] = (short)f2bf(W[(ks * 32 + quad * 8 + j) * 128 + n0 + t * 16 + l15]);
            bfrag[t][ks] = b;
        }

    float asw[4], adw[4];                    // att weights, col = n0+t*16+l15
    #pragma unroll
    for (int t = 0; t < 4; ++t) {
        asw[t] = att_src[n0 + t * 16 + l15];
        adw[t] = att_dst[n0 + t * 16 + l15];
    }

    const int gb = blockIdx.x - NB_PASSA;    // 0..511
    for (int mtb = gb * 2; mtb < M_TILES; mtb += NB_GEMM * 2) {
        // ---- cooperative coalesced staging of tiles mtb, mtb+1 ----
        // 1024 float4 pieces; piece g: tile g>>9, row (g&511)>>5, col4 g&31.
        #pragma unroll
        for (int j = 0; j < 4; ++j) {
            const int g   = tid + j * 256;
            const int tl  = g >> 9;
            const int w   = g & 511;
            const int row = w >> 5;
            const int c4  = w & 31;
            const int mts = mtb + tl;
            if (mts < M_TILES) {
                const float4 u = *(const float4*)&x[(size_t)(mts * 16 + row) * 128 + c4 * 4];
                ushort4 v;
                v.x = f2bf(u.x); v.y = f2bf(u.y); v.z = f2bf(u.z); v.w = f2bf(u.w);
                *(ushort4*)&As[tl][row][c4 * 4] = v;     // 8B LDS store
            }
        }
        __syncthreads();

        const int mt = mtb + (wave >> 1);
        if (mt < M_TILES) {
            const int m0 = mt * 16;
            const int tl = wave >> 1;

            short8 afrag[4];                 // A[m=m0+l15][k=ks*32+quad*8+j]
            #pragma unroll
            for (int ks = 0; ks < 4; ++ks)
                afrag[ks] = *(const short8*)&As[tl][l15][ks * 32 + quad * 8];

            f32x4 acc[4];
            #pragma unroll
            for (int t = 0; t < 4; ++t) acc[t] = (f32x4){0.f, 0.f, 0.f, 0.f};

            #pragma unroll
            for (int ks = 0; ks < 4; ++ks)
                #pragma unroll
                for (int t = 0; t < 4; ++t)
                    acc[t] = __builtin_amdgcn_mfma_f32_16x16x32_bf16(afrag[ks], bfrag[t][ks], acc[t], 0, 0, 0);

            // C/D: row = m0 + quad*4 + r, col = n0 + t*16 + l15
            #pragma unroll
            for (int t = 0; t < 4; ++t)
                #pragma unroll
                for (int r = 0; r < 4; ++r)
                    hb[(m0 + quad * 4 + r) * 128 + n0 + t * 16 + l15] = f2bf(acc[t][r]);

            // fused attention dots: per lane, head g = n0/32 + (t>>1)
            float hs[2][4] = {{0.f,0.f,0.f,0.f},{0.f,0.f,0.f,0.f}};
            float hd[2][4] = {{0.f,0.f,0.f,0.f},{0.f,0.f,0.f,0.f}};
            #pragma unroll
            for (int t = 0; t < 4; ++t)
                #pragma unroll
                for (int r = 0; r < 4; ++r) {
                    hs[t >> 1][r] += acc[t][r] * asw[t];
                    hd[t >> 1][r] += acc[t][r] * adw[t];
                }
            #pragma unroll
            for (int off = 1; off < 16; off <<= 1)
                #pragma unroll
                for (int g = 0; g < 2; ++g)
                    #pragma unroll
                    for (int r = 0; r < 4; ++r) {
                        hs[g][r] += __shfl_xor(hs[g][r], off);
                        hd[g][r] += __shfl_xor(hd[g][r], off);
                    }
            if (l15 == 0) {
                const int hb0 = n0 >> 5;     // first head of this strip
                #pragma unroll
                for (int g = 0; g < 2; ++g)
                    #pragma unroll
                    for (int r = 0; r < 4; ++r) {
                        a_src[(m0 + quad * 4 + r) * 4 + hb0 + g] = hs[g][r];
                        a_dst[(m0 + quad * 4 + r) * 4 + hb0 + g] = hd[g][r];
                    }
            }
        }
        __syncthreads();                     // As reused next iteration
    }
}

// ---- K2: pass B — 256 buckets, LDS binning, coalesced write-out ----

__global__ __launch_bounds__(256) void passB(
    const unsigned int* __restrict__ seg, const int* __restrict__ seg_cnt,
    int* __restrict__ deg, unsigned short* __restrict__ csr_bin)
{
    __shared__ unsigned short bin_l[BWK * BIN];  // 25,088 B
    __shared__ int deg_l[BWK];                   //    784 B
    const int b   = blockIdx.x;                  // bucket = node range
    const int tid = threadIdx.x;
    const int nb  = min(BWK, N_NODES - b * BWK); // 196 (20 for b=255)

    for (int i = tid; i < BWK; i += 256) deg_l[i] = 0;
    __syncthreads();

    // thread t drains source-block t's segment for this bucket (~12 edges)
    const int cnt = seg_cnt[tid * NBKT + b];
    const uint4* s4 = (const uint4*)&seg[((size_t)(tid * NBKT) + b) * CAP];
    for (int i = 0; i < cnt; i += 4) {
        const uint4 u = s4[i >> 2];
        const int rem = cnt - i;
        {
            const int pos = atomicAdd(&deg_l[u.x & 255u], 1);
            if (pos < BIN - 1) bin_l[(u.x & 255u) * BIN + 1 + pos] = (unsigned short)(u.x >> 8);
        }
        if (rem > 1) {
            const int pos = atomicAdd(&deg_l[u.y & 255u], 1);
            if (pos < BIN - 1) bin_l[(u.y & 255u) * BIN + 1 + pos] = (unsigned short)(u.y >> 8);
        }
        if (rem > 2) {
            const int pos = atomicAdd(&deg_l[u.z & 255u], 1);
            if (pos < BIN - 1) bin_l[(u.z & 255u) * BIN + 1 + pos] = (unsigned short)(u.z >> 8);
        }
        if (rem > 3) {
            const int pos = atomicAdd(&deg_l[u.w & 255u], 1);
            if (pos < BIN - 1) bin_l[(u.w & 255u) * BIN + 1 + pos] = (unsigned short)(u.w >> 8);
        }
    }
    __syncthreads();

    // coalesced stream-out: all 196 rows (junk rows >= nb never read)
    uint4* dst = (uint4*)(csr_bin + (size_t)b * BWK * BIN);
    const uint4* srcl = (const uint4*)bin_l;
    constexpr int NVEC = BWK * BIN / 8;          // 1568 16B vectors
    for (int k = tid; k < NVEC; k += 256) dst[k] = srcl[k];
    for (int i = tid; i < nb; i += 256) deg[b * BWK + i] = deg_l[i];
}

// ---- K3: aggregation — wave/node, 2-group-ahead prefetch (8 rows) ----

__global__ __launch_bounds__(256) void gat_agg(
    const int* __restrict__ deg, const unsigned short* __restrict__ csr_bin,
    const unsigned short* __restrict__ hb, const float* __restrict__ a_src,
    const float* __restrict__ a_dst, const float* __restrict__ bias,
    float* __restrict__ out)
{
    __shared__ float ws[4][256];             // [wave][edge*4 + head]
    const int wv = threadIdx.x >> 6;
    const int node = blockIdx.x * 4 + wv;
    if (node >= N_NODES) return;
    const int lane = threadIdx.x & 63;
    const int q    = lane >> 4;              // quarter: which edge of the 4
    const int li   = lane & 15;
    const int ch0  = li * 8;                 // 8 channels per lane
    const int hd   = li >> 2;                // head of my channels (ch0/32)
    const float4 ad4 = *(const float4*)&a_dst[node * 4];
    int m = deg[node] + 1;                   // self loop included
    if (m > BIN) m = BIN;                    // never fires (max deg ~45)

    // lane 0 = self loop (synthesized), lanes [1,m) = binned in-edges
    int sv = 0;
    if (lane < m)
        sv = (lane == 0) ? node : (int)csr_bin[(size_t)node * BIN + lane];
    if (lane < m) {
        const float4 av = *(const float4*)&a_src[sv * 4];
        float t; float4 w4;
        t = av.x + ad4.x; t = t > 0.f ? t : NEG_SLOPE * t; w4.x = __expf(t);
        t = av.y + ad4.y; t = t > 0.f ? t : NEG_SLOPE * t; w4.y = __expf(t);
        t = av.z + ad4.z; t = t > 0.f ? t : NEG_SLOPE * t; w4.z = __expf(t);
        t = av.w + ad4.w; t = t > 0.f ? t : NEG_SLOPE * t; w4.w = __expf(t);
        *(float4*)&ws[wv][lane * 4] = w4;    // all 4 head weights for my edge
    }

    float acc[8] = {0.f,0.f,0.f,0.f,0.f,0.f,0.f,0.f};
    float dsum = 0.f;

    // 2-group-ahead software pipeline: groups j, j+1 in registers, j+2 in
    // flight -> 8 rows outstanding per wave during compute.
    const int i0 = (q < m) ? q : 0;
    uint4 hv0 = *(const uint4*)&hb[(size_t)__shfl(sv, i0) * 128 + ch0];
    const int e1 = 4 + q;
    const int i1 = (e1 < m) ? e1 : 0;
    uint4 hv1 = *(const uint4*)&hb[(size_t)__shfl(sv, i1) * 128 + ch0];

    for (int j = 0; j < m; j += 4) {
        const int en  = j + 8 + q;           // group j+2's edge for my quarter
        const int idn = en < m ? en : 0;     // clamp -> dup row (L1-hot)
        const int s_n = __shfl(sv, idn);
        const uint4 hv2 = *(const uint4*)&hb[(size_t)s_n * 128 + ch0];

        const int ei  = j + q;
        const int idx = ei < m ? ei : j;     // edge whose row is in hv0
        float w = ws[wv][idx * 4 + hd];
        if (ei >= m) w = 0.f;
        acc[0] += w * __uint_as_float(hv0.x << 16);
        acc[1] += w * __uint_as_float(hv0.x & 0xFFFF0000u);
        acc[2] += w * __uint_as_float(hv0.y << 16);
        acc[3] += w * __uint_as_float(hv0.y & 0xFFFF0000u);
        acc[4] += w * __uint_as_float(hv0.z << 16);
        acc[5] += w * __uint_as_float(hv0.z & 0xFFFF0000u);
        acc[6] += w * __uint_as_float(hv0.w << 16);
        acc[7] += w * __uint_as_float(hv0.w & 0xFFFF0000u);
        dsum += w;
        hv0 = hv1; hv1 = hv2;
    }

    // combine the four quarters (disjoint edge subsets, same channels)
    #pragma unroll
    for (int off = 16; off <= 32; off <<= 1) {
        #pragma unroll
        for (int r = 0; r < 8; ++r) acc[r] += __shfl_xor(acc[r], off);
        dsum += __shfl_xor(dsum, off);
    }
    if (q == 0) {
        const float inv = 1.f / dsum;        // dsum >= exp(self) > 0
        const float4 b0 = *(const float4*)&bias[ch0];
        const float4 b1 = *(const float4*)&bias[ch0 + 4];
        float4 o0, o1;
        o0.x = acc[0]*inv + b0.x; o0.y = acc[1]*inv + b0.y;
        o0.z = acc[2]*inv + b0.z; o0.w = acc[3]*inv + b0.w;
        o1.x = acc[4]*inv + b1.x; o1.y = acc[5]*inv + b1.y;
        o1.z = acc[6]*inv + b1.z; o1.w = acc[7]*inv + b1.w;
        *(float4*)&out[(size_t)node * HC + ch0]     = o0;
        *(float4*)&out[(size_t)node * HC + ch0 + 4] = o1;
    }
}

extern "C" void kernel_launch(void* const* d_in, const int* in_sizes, int n_in,
                              void* d_out, int out_size, void* d_ws, size_t ws_size,
                              hipStream_t stream) {
    const float* x       = (const float*)d_in[0];
    const int*   ei      = (const int*)  d_in[1];   // [2,E]: row0=src, row1=dst
    const float* W       = (const float*)d_in[2];
    const float* att_src = (const float*)d_in[3];
    const float* att_dst = (const float*)d_in[4];
    const float* bias    = (const float*)d_in[5];
    float* out = (float*)d_out;

    // ws layout (~31 MB): hb | a_src | a_dst | csr_bin(u16) | deg | seg | seg_cnt
    char* p = (char*)d_ws;
    unsigned short* hb  = (unsigned short*)p; p += (size_t)N_NODES * HC * 2;  // 12.8 MB
    float* a_src = (float*)p; p += (size_t)N_NODES * 4 * 4;                   // 800 KB
    float* a_dst = (float*)p; p += (size_t)N_NODES * 4 * 4;
    unsigned short* csr_bin = (unsigned short*)p; p += (size_t)NBKT * BWK * BIN * 2; // 6.42 MB
    int* deg     = (int*)p;   p += N_NODES * 4;
    unsigned int* seg = (unsigned int*)p; p += (size_t)NB_PASSA * NBKT * CAP * 4;   // 9.44 MB
    int* seg_cnt = (int*)p;   p += NB_PASSA * NBKT * 4;                             // 256 KB

    const int* esrc = ei;
    const int* edst = ei + N_EDGES;

    gemm_passA<<<NB_PASSA + NB_GEMM, 256, 0, stream>>>(x, W, att_src, att_dst,
                                                       esrc, edst, hb, a_src, a_dst,
                                                       seg, seg_cnt);
    passB     <<<NBKT, 256, 0, stream>>>(seg, seg_cnt, deg, csr_bin);
    gat_agg   <<<(N_NODES + 3) / 4, 256, 0, stream>>>(deg, csr_bin, hb, a_src,
                                                      a_dst, bias, out);
}